// Round 6
// baseline (313.525 us; speedup 1.0000x reference)
//
#include <hip/hip_runtime.h>
#include <stdint.h>

#define N_PTS 131072
#define NC 256
#define NSEG 16
#define BN_EPSF 1e-5f

typedef __attribute__((ext_vector_type(8))) short bf16x8;
typedef __attribute__((ext_vector_type(4))) float f32x4;

__device__ __forceinline__ unsigned short f2bf(float f) {
  union { float f; uint32_t u; } v; v.f = f;
  uint32_t u = v.u;
  uint32_t r = (u + 0x7fffu + ((u >> 16) & 1u)) >> 16;
  return (unsigned short)r;
}
__device__ __forceinline__ float bf2f(unsigned short h) {
  union { uint32_t u; float f; } v; v.u = ((uint32_t)h) << 16; return v.f;
}

// LDS-visibility-only barrier: drains LDS ops (so producer writes are visible
// to consumers after the barrier) but does NOT drain vmcnt — global prefetch
// loads and g_bf stores stay in flight across it (unlike __syncthreads, which
// emits s_waitcnt vmcnt(0) and serializes HBM latency onto every tile).
__device__ __forceinline__ void bar_lds() {
  asm volatile("s_waitcnt lgkmcnt(0)" ::: "memory");
  __builtin_amdgcn_s_barrier();
}

// Chunk swizzle for lA: within each 64-col (128B) window of a row, XOR the
// 8-col (16B) chunk index with (row&7). Writes pre-swizzle, ds_read_b128
// applies the same XOR -> 2-way bank aliasing (free) instead of 8/16-way.
__device__ __forceinline__ int swz(int col, int row) {
  return (col & ~63) | ((((col >> 3) & 7) ^ (row & 7)) << 3) | (col & 7);
}

// ---- prep: blocks 0..15 transpose+convert W1_top (plain layout); 16.. zero stats ----
__global__ __launch_bounds__(256) void k_prep(const float* __restrict__ W1,
                                              unsigned short* __restrict__ w1t,
                                              float* __restrict__ zerobuf) {
  int b = blockIdx.x, t = threadIdx.x;
  if (b >= 16) {
    int i = (b - 16) * 256 + t;
    if (i < 8448) zerobuf[i] = 0.f;  // seg_sums(4096)+hseg(4096)+gsumsq(256)
    return;
  }
  __shared__ float tile[64][65];
  int bx = b & 3, by = b >> 2;
  int k0 = by * 64, j0 = bx * 64;
  int r = t >> 6, c = t & 63;
#pragma unroll
  for (int i = 0; i < 16; ++i) {
    int kk = r + i * 4;
    tile[kk][c] = W1[(size_t)(k0 + kk) * NC + j0 + c];
  }
  __syncthreads();
#pragma unroll
  for (int i = 0; i < 16; ++i) {
    int jj = r + i * 4;
    w1t[(size_t)(j0 + jj) * NC + k0 + c] = f2bf(tile[c][jj]);  // plain [col][k]
  }
}

// ---- GEMM (persistent-tile pipeline): 512 blocks x 512 thr (8 waves),
// block owns 4 consecutive 64-row tiles (256 rows -> at most ONE segment
// boundary: per-block constant sA,sB,e). B=w1t lives in registers (16 frags).
// lA double-buffered; 1 lgkm-only barrier/tile; x loads for tile t+1 stay in
// flight across the barrier and land under tile t's MFMA.
__global__ __launch_bounds__(512, 2) void k_gemm1(
    const float* __restrict__ x, const int* __restrict__ o,
    const unsigned short* __restrict__ w1t,
    unsigned short* __restrict__ g_bf,
    float* __restrict__ seg_sums, float* __restrict__ hseg,
    float* __restrict__ gsumsq) {
  __shared__ __align__(16) unsigned short lA[2][64 * NC];   // 2 x 32 KiB, swizzled
  __shared__ float s_xacc[2][NC];
  __shared__ float s_gA[NC], s_gB[NC], s_gq[NC];
  __shared__ int o_s[NSEG];
  int t = threadIdx.x, lane = t & 63, w = t >> 6;
  int rowB = blockIdx.x * 256;
  if (t < NSEG) o_s[t] = o[t];
  if (t < NC) { s_xacc[0][t] = 0.f; s_xacc[1][t] = 0.f; }
  __syncthreads();
  int sA = 0;
  while (o_s[sA] <= rowB) ++sA;
  int e = o_s[sA];
  int sB = (sA < NSEG - 1) ? sA + 1 : sA;

  // B fragments in registers, loaded once (w1t is L2-resident, 128 KiB)
  bf16x8 Bf[4][2][2];  // [kt][kk][nn]
  {
    int jr0 = w * 32 + (lane & 15);
    int sl0 = lane >> 4;
#pragma unroll
    for (int kt = 0; kt < 4; ++kt)
#pragma unroll
      for (int kk = 0; kk < 2; ++kk)
#pragma unroll
        for (int nn = 0; nn < 2; ++nn)
          Bf[kt][kk][nn] = *(const bf16x8*)(
              w1t + (size_t)(jr0 + nn * 16) * NC + kt * 64 + (kk * 4 + sl0) * 8);
  }

  // stats: accumulate TOTAL and A-part; B = T - A at flush (fewer selects)
  float4 xaccT = {0.f, 0.f, 0.f, 0.f}, xaccA = {0.f, 0.f, 0.f, 0.f};
  f32x4 pT[2] = {}, pA[2] = {}, pq[2] = {};
  f32x4 acc[4][2] = {};
  const float4* xv = (const float4*)x;
  int c0 = lane * 4;
  float4 xr[8];
  // preload tile 0 (8 coalesced float4/thread; wave w covers rows w+8i)
#pragma unroll
  for (int i = 0; i < 8; ++i)
    xr[i] = xv[(size_t)(rowB + w + i * 8) * 64 + lane];

  for (int tile = 0; tile < 4; ++tile) {
    int row0 = rowB + tile * 64;
    int buf = tile & 1;
    // convert + x seg-sums + stage current tile into lA[buf]
#pragma unroll
    for (int i = 0; i < 8; ++i) {
      int rl = w + i * 8;
      int r = row0 + rl;
      float4 v = xr[i];
      ushort4 b;
      b.x = f2bf(v.x); b.y = f2bf(v.y); b.z = f2bf(v.z); b.w = f2bf(v.w);
      *(ushort4*)(&lA[buf][rl * NC + swz(c0, rl)]) = b;
      xaccT.x += v.x; xaccT.y += v.y; xaccT.z += v.z; xaccT.w += v.w;
      bool inA = (r < e);
      xaccA.x += inA ? v.x : 0.f;
      xaccA.y += inA ? v.y : 0.f;
      xaccA.z += inA ? v.z : 0.f;
      xaccA.w += inA ? v.w : 0.f;
    }
    // issue loads for next tile; they stay in flight across bar_lds (no vmcnt drain)
    if (tile < 3) {
#pragma unroll
      for (int i = 0; i < 8; ++i)
        xr[i] = xv[(size_t)(row0 + 64 + w + i * 8) * 64 + lane];
    }
    bar_lds();  // publish lA[buf]; buf^1 writes next iter can't race (other buffer)

    // 32 ds_read_b128 + 32 MFMA per wave
#pragma unroll
    for (int kt = 0; kt < 4; ++kt)
#pragma unroll
      for (int kk = 0; kk < 2; ++kk) {
        bf16x8 af[4];
        int sl = kk * 4 + (lane >> 4);
#pragma unroll
        for (int mm = 0; mm < 4; ++mm) {
          int r = mm * 16 + (lane & 15);
          af[mm] = *(const bf16x8*)(&lA[buf][r * NC + kt * 64 + ((sl ^ (r & 7)) << 3)]);
        }
#pragma unroll
        for (int mm = 0; mm < 4; ++mm)
#pragma unroll
          for (int nn = 0; nn < 2; ++nn)
            acc[mm][nn] = __builtin_amdgcn_mfma_f32_16x16x32_bf16(
                Bf[kt][kk][nn], af[mm], acc[mm][nn], 0, 0, 0);
      }

    // per-tile epilogue: g_bf store + reg-accumulated stats, reset acc
    int rl = lane & 15, q = lane >> 4;
#pragma unroll
    for (int mm = 0; mm < 4; ++mm) {
      int row = row0 + mm * 16 + rl;
      bool inA = (row < e);
#pragma unroll
      for (int nn = 0; nn < 2; ++nn) {
        f32x4 g = acc[mm][nn];
        ushort4 b;
        b.x = f2bf(g[0]); b.y = f2bf(g[1]); b.z = f2bf(g[2]); b.w = f2bf(g[3]);
        *(ushort4*)(g_bf + (size_t)row * NC + w * 32 + nn * 16 + q * 4) = b;
        pT[nn] += g;
        if (inA) pA[nn] += g;
        pq[nn] += g * g;
        acc[mm][nn] = (f32x4){0.f, 0.f, 0.f, 0.f};
      }
    }
  }

  // block-level flush (once); B-parts derived as T - A
  atomicAdd(&s_xacc[0][c0 + 0], xaccA.x);
  atomicAdd(&s_xacc[0][c0 + 1], xaccA.y);
  atomicAdd(&s_xacc[0][c0 + 2], xaccA.z);
  atomicAdd(&s_xacc[0][c0 + 3], xaccA.w);
  atomicAdd(&s_xacc[1][c0 + 0], xaccT.x - xaccA.x);
  atomicAdd(&s_xacc[1][c0 + 1], xaccT.y - xaccA.y);
  atomicAdd(&s_xacc[1][c0 + 2], xaccT.z - xaccA.z);
  atomicAdd(&s_xacc[1][c0 + 3], xaccT.w - xaccA.w);
#pragma unroll
  for (int nn = 0; nn < 2; ++nn)
#pragma unroll
    for (int j = 0; j < 4; ++j) {
      float a = pA[nn][j], bb = pT[nn][j] - pA[nn][j], qq = pq[nn][j];
      a += __shfl_xor(a, 1, 64); a += __shfl_xor(a, 2, 64);
      a += __shfl_xor(a, 4, 64); a += __shfl_xor(a, 8, 64);
      bb += __shfl_xor(bb, 1, 64); bb += __shfl_xor(bb, 2, 64);
      bb += __shfl_xor(bb, 4, 64); bb += __shfl_xor(bb, 8, 64);
      qq += __shfl_xor(qq, 1, 64); qq += __shfl_xor(qq, 2, 64);
      qq += __shfl_xor(qq, 4, 64); qq += __shfl_xor(qq, 8, 64);
      pA[nn][j] = a; pT[nn][j] = bb; pq[nn][j] = qq;  // reuse pT as B-part
    }
  if ((lane & 15) == 0) {
    int q = lane >> 4;
#pragma unroll
    for (int nn = 0; nn < 2; ++nn) {
      int cb = w * 32 + nn * 16 + q * 4;   // wave-exclusive cols: plain stores
#pragma unroll
      for (int j = 0; j < 4; ++j) {
        s_gA[cb + j] = pA[nn][j];
        s_gB[cb + j] = pT[nn][j];
        s_gq[cb + j] = pq[nn][j];
      }
    }
  }
  __syncthreads();
  if (t < NC) {
    atomicAdd(&seg_sums[sA * NC + t], s_xacc[0][t]);
    atomicAdd(&seg_sums[sB * NC + t], s_xacc[1][t]);
    atomicAdd(&hseg[sA * NC + t], s_gA[t]);
    atomicAdd(&hseg[sB * NC + t], s_gB[t]);
    atomicAdd(&gsumsq[t], s_gq[t]);
  }
}

// ---- tiny per-segment MLP: means -> y=relu(means@W2+b2) -> z=y@W1_bot+b1 ----
__global__ __launch_bounds__(256) void k_seg_mlp(
    const int* __restrict__ o, const float* __restrict__ seg_sums,
    const float* __restrict__ W1, const float* __restrict__ b1,
    const float* __restrict__ W2, const float* __restrict__ b2,
    float* __restrict__ z) {
  __shared__ float mean_s[NC];
  __shared__ float y_s[NC];
  int b = blockIdx.x, j = threadIdx.x;
  int start = (b == 0) ? 0 : o[b - 1];
  float inv = 1.f / (float)(o[b] - start);
  mean_s[j] = seg_sums[b * NC + j] * inv;
  __syncthreads();
  float a = b2[j];
  for (int k = 0; k < NC; ++k) a += mean_s[k] * W2[k * NC + j];
  y_s[j] = fmaxf(a, 0.f);
  __syncthreads();
  float a2 = b1[j];
  for (int k = 0; k < NC; ++k) a2 += y_s[k] * W1[(NC + k) * NC + j];
  z[b * NC + j] = a2;
}

// ---- apply: BN finalize (decomposed stats) + out = relu((g+z[seg])*sc+sh) ----
__global__ __launch_bounds__(256) void k_apply(
    const unsigned short* __restrict__ g_bf, const int* __restrict__ o,
    const float* __restrict__ z, const float* __restrict__ hseg,
    const float* __restrict__ gsumsq, const float* __restrict__ gamma,
    const float* __restrict__ beta, float* __restrict__ out) {
  __shared__ float s_scale[NC], s_shift[NC];
  __shared__ int o_s[NSEG];
  int t = threadIdx.x;
  int row0 = blockIdx.x * 64;
  if (t < NSEG) o_s[t] = o[t];
  __syncthreads();
  {  // colsum = Σ hseg + Σ cnt·z ; colsumsq = gsumsq + Σ(2·hseg+cnt·z)·z
    float cs = 0.f, cq = gsumsq[t];
    int prev = 0;
#pragma unroll
    for (int s = 0; s < NSEG; ++s) {
      float cnt = (float)(o_s[s] - prev);
      prev = o_s[s];
      float hs = hseg[s * NC + t], zz = z[s * NC + t];
      cs += hs + cnt * zz;
      cq += (2.f * hs + cnt * zz) * zz;
    }
    float invN = 1.f / (float)N_PTS;
    float mu = cs * invN;
    float var = cq * invN - mu * mu;
    float sc = gamma[t] * rsqrtf(var + BN_EPSF);
    s_scale[t] = sc;
    s_shift[t] = beta[t] - mu * sc;
  }
  __syncthreads();
  int s0 = 0;
  while (o_s[s0] <= row0) ++s0;
  int e0 = o_s[s0];
  int s1 = (s0 < NSEG - 1) ? s0 + 1 : s0;
  int cg = (t & 31) * 8, rsub = t >> 5;
  float4 sc0 = *(const float4*)(s_scale + cg), sc1 = *(const float4*)(s_scale + cg + 4);
  float4 sh0 = *(const float4*)(s_shift + cg), sh1 = *(const float4*)(s_shift + cg + 4);
  float4 zA0 = *(const float4*)(z + s0 * NC + cg), zA1 = *(const float4*)(z + s0 * NC + cg + 4);
  float4 zB0 = *(const float4*)(z + s1 * NC + cg), zB1 = *(const float4*)(z + s1 * NC + cg + 4);
#pragma unroll
  for (int i = 0; i < 8; ++i) {
    int row = row0 + rsub + i * 8;
    uint4 hv = *(const uint4*)(g_bf + (size_t)row * NC + cg);
    bool inA = (row < e0);
    float4 z0 = inA ? zA0 : zB0;
    float4 z1 = inA ? zA1 : zB1;
    float4 o0, o1;
    o0.x = fmaxf((bf2f((unsigned short)(hv.x & 0xffffu)) + z0.x) * sc0.x + sh0.x, 0.f);
    o0.y = fmaxf((bf2f((unsigned short)(hv.x >> 16)) + z0.y) * sc0.y + sh0.y, 0.f);
    o0.z = fmaxf((bf2f((unsigned short)(hv.y & 0xffffu)) + z0.z) * sc0.z + sh0.z, 0.f);
    o0.w = fmaxf((bf2f((unsigned short)(hv.y >> 16)) + z0.w) * sc0.w + sh0.w, 0.f);
    o1.x = fmaxf((bf2f((unsigned short)(hv.z & 0xffffu)) + z1.x) * sc1.x + sh1.x, 0.f);
    o1.y = fmaxf((bf2f((unsigned short)(hv.z >> 16)) + z1.y) * sc1.y + sh1.y, 0.f);
    o1.z = fmaxf((bf2f((unsigned short)(hv.w & 0xffffu)) + z1.z) * sc1.z + sh1.z, 0.f);
    o1.w = fmaxf((bf2f((unsigned short)(hv.w >> 16)) + z1.w) * sc1.w + sh1.w, 0.f);
    *(float4*)(out + (size_t)row * NC + cg) = o0;
    *(float4*)(out + (size_t)row * NC + cg + 4) = o1;
  }
}

extern "C" void kernel_launch(void* const* d_in, const int* in_sizes, int n_in,
                              void* d_out, int out_size, void* d_ws, size_t ws_size,
                              hipStream_t stream) {
  const float* x = (const float*)d_in[0];
  const int* o = (const int*)d_in[1];
  const float* W1 = (const float*)d_in[2];
  const float* b1 = (const float*)d_in[3];
  const float* W2 = (const float*)d_in[4];
  const float* b2 = (const float*)d_in[5];
  const float* gamma = (const float*)d_in[6];
  const float* beta = (const float*)d_in[7];
  float* out = (float*)d_out;

  char* ws = (char*)d_ws;
  unsigned short* g_bf = (unsigned short*)ws;          // 64 MiB
  char* base2 = ws + 67108864;
  float* seg_sums = (float*)(base2);                   // 16 KiB (zeroed)
  float* hseg     = (float*)(base2 + 16384);           // 16 KiB (zeroed)
  float* gsumsq   = (float*)(base2 + 32768);           // 1 KiB  (zeroed)
  float* z        = (float*)(base2 + 33792);           // 16 KiB
  unsigned short* w1t = (unsigned short*)(base2 + 50176);  // 128 KiB, plain [col][k]

  k_prep<<<49, 256, 0, stream>>>(W1, w1t, seg_sums);   // zeroes seg_sums..gsumsq
  k_gemm1<<<512, 512, 0, stream>>>(x, o, w1t, g_bf, seg_sums, hseg, gsumsq);
  k_seg_mlp<<<16, 256, 0, stream>>>(o, seg_sums, W1, b1, W2, b2, z);
  k_apply<<<2048, 256, 0, stream>>>(g_bf, o, z, hseg, gsumsq, gamma, beta, out);
}